// Round 6
// baseline (3865.044 us; speedup 1.0000x reference)
//
#include <hip/hip_runtime.h>
#include <hip/hip_bf16.h>
#include <math.h>

#define N_NODES 50000
#define E_EDGES 800000
#define S_DIM 128
#define V_DIM 16
#define HM 17            // message GVP dim_h / vectors-in
#define KM 161           // 128 + 16 rbf + 17 sh
#define HU 32            // update GVP vectors-in
#define KU 288           // 256 + 32 sh

#define EB 32            // edges per tile
#define DPB 8            // dst nodes owned per block (8 | 50000)
#define LDA 164          // A-tile leading dim (161 used)
#define NB 32            // nodes per block (node kernel)
#define LDA2 292         // node A-tile leading dim (288 used)

__device__ __forceinline__ float bf2f(unsigned short u) {
    union { unsigned int i; float f; } w; w.i = ((unsigned int)u) << 16; return w.f;
}
__device__ __forceinline__ unsigned short f2bf(float f) {
    union { float f; unsigned int i; } w; w.f = f;
    unsigned int x = w.i;
    x += 0x7fff + ((x >> 16) & 1);
    return (unsigned short)(x >> 16);
}
__device__ __forceinline__ float silu_f(float x) { return x / (1.f + __expf(-x)); }
__device__ __forceinline__ float sigm_f(float x) { return 1.f / (1.f + __expf(-x)); }
__device__ __forceinline__ float ldf(const void* p, int i, int m) {
    if (m) return ((const float*)p)[i];
    return bf2f(((const unsigned short*)p)[i]);
}

// ---------------------------------------------------------------------------
// Detector: fp32 (flag=1) vs bf16 (flag=0) float inputs.
// ---------------------------------------------------------------------------
__global__ void detect_kernel(const unsigned short* __restrict__ s_us,
                              int* __restrict__ flag) {
    int t = threadIdx.x;
    int huge = 0;
    for (int k = 0; k < 16; ++k) {
        unsigned short u = s_us[2 * (t + 64 * k)];
        int e = (u >> 7) & 0xFF;
        if (e > 140) huge = 1;
    }
    if (huge) atomicOr(flag, 1);
}

// ---------------------------------------------------------------------------
// CSR build: histogram -> exclusive scan (row_ptr + cursor) -> scatter.
// ---------------------------------------------------------------------------
__global__ __launch_bounds__(256) void hist_kernel(const int* __restrict__ ei,
                                                   int* __restrict__ deg) {
    int e = blockIdx.x * 256 + threadIdx.x;
    if (e < E_EDGES) atomicAdd(&deg[ei[E_EDGES + e]], 1);
}

__global__ __launch_bounds__(1024) void scan_kernel(const int* __restrict__ deg,
                                                    int* __restrict__ cursor,
                                                    int* __restrict__ row_ptr) {
    __shared__ int part[1024];
    const int t = threadIdx.x;
    const int CH = 49;                      // 1024*49 >= 50000
    int base = t * CH;
    int s = 0;
    for (int i = 0; i < CH; ++i) {
        int idx = base + i;
        if (idx < N_NODES) s += deg[idx];
    }
    part[t] = s;
    __syncthreads();
    if (t == 0) {
        int run = 0;
        for (int i = 0; i < 1024; ++i) { int tmp = part[i]; part[i] = run; run += tmp; }
    }
    __syncthreads();
    int run = part[t];
    for (int i = 0; i < CH; ++i) {
        int idx = base + i;
        if (idx < N_NODES) { cursor[idx] = run; row_ptr[idx] = run; run += deg[idx]; }
    }
}

__global__ __launch_bounds__(256) void scatter_kernel(const int* __restrict__ ei,
                                                      int* __restrict__ cursor,
                                                      int* __restrict__ ssrc,
                                                      int* __restrict__ sdst) {
    int e = blockIdx.x * 256 + threadIdx.x;
    if (e >= E_EDGES) return;
    int src = ei[e], dst = ei[E_EDGES + e];
    int pos = atomicAdd(&cursor[dst], 1);
    ssrc[pos] = src;
    sdst[pos] = dst;
}

// ---------------------------------------------------------------------------
// Edge (message) kernel, node-centric: block owns dsts [d0, d0+8) and ALL
// their in-edges (CSR range), processed in 32-edge tiles. Messages reduced
// into LDS agg[8][176]; written once with plain stores. ZERO global atomics.
// ---------------------------------------------------------------------------
__global__ __launch_bounds__(256, 4) void edge_kernel(
    const void* sP, const void* vP, const void* xP,
    const void* WhP, const void* WuP, const void* WfP,
    const void* bfP, const void* WgP, const void* bgP,
    const int* __restrict__ row_ptr,
    const int* __restrict__ ssrc,
    const int* __restrict__ sdst,
    const int* __restrict__ flagp,
    float* __restrict__ agg_s,               // [N][128]
    float* __restrict__ agg_v)               // [N][48]
{
    __shared__ float A[EB * LDA];        // 20992 B: 0..127 s->feats, 128..143 rbf, 144..160 sh
    __shared__ float Bs[2048];           // 8192 B: vin [32][52] + Wu@1664 | Wf chunks | Wg | mv [32][48]
    __shared__ float WhWu[HM * 16];      // 1088 B
    __shared__ float WhS[HM * HM + 3];   // 1168 B (persistent Wh)
    __shared__ float gates[EB * 16];     // 2048 B
    __shared__ float agg[DPB * 176];     // 5632 B accumulators
    __shared__ int srcb[EB], dstb[EB];   // 256 B (dstb is RELATIVE to d0)

    const int t = threadIdx.x;
    const int m = flagp[0];              // 1 = fp32 inputs
    const int d0 = blockIdx.x * DPB;
    const int e_beg = row_ptr[d0];
    const int e_end = (d0 + DPB >= N_NODES) ? E_EDGES : row_ptr[d0 + DPB];

    // block-once: zero agg, stage Wh -> WhS, Wu -> Bs[1664..1935]
    for (int i = t; i < DPB * 176; i += 256) agg[i] = 0.f;
    if (m) {
        const float* Wh = (const float*)WhP;
        const float* Wu = (const float*)WuP;
        for (int i = t; i < HM * HM; i += 256) WhS[i] = Wh[i];
        for (int i = t; i < HM * 16; i += 256) Bs[1664 + i] = Wu[i];
    } else {
        const unsigned short* Wh = (const unsigned short*)WhP;
        const unsigned short* Wu = (const unsigned short*)WuP;
        for (int i = t; i < HM * HM; i += 256) WhS[i] = bf2f(Wh[i]);
        for (int i = t; i < HM * 16; i += 256) Bs[1664 + i] = bf2f(Wu[i]);
    }
    __syncthreads();
    // WhWu = Wh @ Wu  [17][16]
    for (int idx = t; idx < HM * 16; idx += 256) {
        int vv = idx / 16, o = idx % 16;
        float acc = 0.f;
        for (int h = 0; h < HM; ++h)
            acc += WhS[vv * HM + h] * Bs[1664 + h * 16 + o];
        WhWu[idx] = acc;
    }
    __syncthreads();   // Bs (Wu stash) free after this

    const int tj = t & 15, te = t >> 4;
    const int eb = te * 2;

    for (int et = e_beg; et < e_end; et += EB) {
        const int cnt = min(EB, e_end - et);
        // tile indices (dummy node 0 for padded slots; never accumulated)
        if (t < EB) {
            srcb[t] = (t < cnt) ? ssrc[et + t] : 0;
            dstb[t] = (t < cnt) ? (sdst[et + t] - d0) : 0;
        }
        __syncthreads();
        // s-gather into A cols 0..127
        {
            int cj = t & 31, ce = t >> 5;
            if (m) {
                const float* sF = (const float*)sP;
                for (int r = 0; r < 4; ++r) {
                    int e = ce + 8 * r;
                    float4 u = *(const float4*)(sF + (size_t)srcb[e] * S_DIM + cj * 4);
                    float* a = &A[e * LDA + cj * 4];
                    a[0] = u.x; a[1] = u.y; a[2] = u.z; a[3] = u.w;
                }
            } else {
                const unsigned short* sU = (const unsigned short*)sP;
                for (int r = 0; r < 4; ++r) {
                    int e = ce + 8 * r;
                    ushort4 u = *(const ushort4*)(sU + (size_t)srcb[e] * S_DIM + cj * 4);
                    float* a = &A[e * LDA + cj * 4];
                    a[0] = bf2f(u.x); a[1] = bf2f(u.y); a[2] = bf2f(u.z); a[3] = bf2f(u.w);
                }
            }
        }
        // vin into Bs[e][52] + geometry/rbf
        if (t < 128) {
            int e = t >> 2, q = t & 3;
            int src = srcb[e];
            float* vin = &Bs[e * 52 + q * 12];
            if (m) {
                const float* vp = (const float*)vP + (size_t)src * 48 + q * 12;
                for (int i = 0; i < 3; ++i) {
                    float4 u = *(const float4*)(vp + i * 4);
                    vin[i * 4 + 0] = u.x; vin[i * 4 + 1] = u.y;
                    vin[i * 4 + 2] = u.z; vin[i * 4 + 3] = u.w;
                }
            } else {
                const unsigned short* vp = (const unsigned short*)vP + (size_t)src * 48 + q * 12;
                for (int i = 0; i < 3; ++i) {
                    ushort4 u = *(const ushort4*)(vp + i * 4);
                    vin[i * 4 + 0] = bf2f(u.x); vin[i * 4 + 1] = bf2f(u.y);
                    vin[i * 4 + 2] = bf2f(u.z); vin[i * 4 + 3] = bf2f(u.w);
                }
            }
            if (q == 0) {
                int dst = d0 + dstb[e];                  // absolute dst node
                float dxc[3]; float d2 = 0.f;
                for (int c = 0; c < 3; ++c) {
                    float xs = ldf(xP, src * 3 + c, m);
                    float xd = ldf(xP, dst * 3 + c, m);
                    dxc[c] = xd - xs; d2 += dxc[c] * dxc[c];
                }
                float dist = sqrtf(fmaxf(d2, 1e-8f));
                float inv = 1.f / dist;
                for (int c = 0; c < 3; ++c) Bs[e * 52 + 48 + c] = dxc[c] * inv;
                for (int k = 0; k < 16; ++k) {
                    float mu = (20.f / 15.f) * (float)k;
                    float z = (dist - mu) * (1.f / 1.25f);
                    A[e * LDA + 128 + k] = __expf(-z * z);
                }
            }
        }
        __syncthreads();
        // sh -> A cols 144..160
        for (int idx = t; idx < EB * HM; idx += 256) {
            int e = idx / HM, h = idx % HM;
            const float* vin = &Bs[e * 52];
            float vh0 = 0.f, vh1 = 0.f, vh2 = 0.f;
            for (int vv = 0; vv < HM; ++vv) {
                float w = WhS[vv * HM + h];
                vh0 += vin[vv * 3 + 0] * w;
                vh1 += vin[vv * 3 + 1] * w;
                vh2 += vin[vv * 3 + 2] * w;
            }
            A[e * LDA + 144 + h] = sqrtf(fmaxf(vh0 * vh0 + vh1 * vh1 + vh2 * vh2, 1e-8f));
        }
        // Vu into registers (6 per thread, flat 32*48)
        float vureg[6];
        for (int r = 0; r < 6; ++r) {
            int idx = t + 256 * r;
            int e = idx / 48, oc = idx % 48, o = oc / 3, c = oc % 3;
            const float* vin = &Bs[e * 52];
            float acc = 0.f;
            for (int vv = 0; vv < HM; ++vv)
                acc += vin[vv * 3 + c] * WhWu[vv * 16 + o];
            vureg[r] = acc;
        }
        __syncthreads();   // Bs vin free

        // GEMM feats[32][128] = A[32][161] @ Wf  (round-4 conflict-free form)
        float acc[2][8];
        #pragma unroll
        for (int i = 0; i < 2; ++i)
            #pragma unroll
            for (int j = 0; j < 8; ++j) acc[i][j] = 0.f;

        for (int kk = 0; kk < KM; kk += 16) {
            int kmax = min(16, KM - kk);
            if (m) {
                const float* WfF = (const float*)WfP;
                for (int idx = t; idx < kmax * 32; idx += 256) {
                    int kt = idx >> 5, col4 = (idx & 31) * 4;
                    float4 u = *(const float4*)(WfF + (size_t)(kk + kt) * 128 + col4);
                    float* b = &Bs[kt * 128 + col4];
                    b[0] = u.x; b[1] = u.y; b[2] = u.z; b[3] = u.w;
                }
            } else {
                const unsigned short* WfU = (const unsigned short*)WfP;
                for (int idx = t; idx < kmax * 32; idx += 256) {
                    int kt = idx >> 5, col4 = (idx & 31) * 4;
                    ushort4 u = *(const ushort4*)(WfU + (size_t)(kk + kt) * 128 + col4);
                    float* b = &Bs[kt * 128 + col4];
                    b[0] = bf2f(u.x); b[1] = bf2f(u.y); b[2] = bf2f(u.z); b[3] = bf2f(u.w);
                }
            }
            __syncthreads();
            for (int kt = 0; kt < kmax; ++kt) {
                float a0 = A[(eb + 0) * LDA + kk + kt];
                float a1 = A[(eb + 1) * LDA + kk + kt];
                const float* brow = &Bs[kt * 128 + tj];
                #pragma unroll
                for (int jj = 0; jj < 8; ++jj) {
                    float b = brow[16 * jj];
                    acc[0][jj] += a0 * b; acc[1][jj] += a1 * b;
                }
            }
            __syncthreads();
        }
        // bias + silu -> feats into A cols 0..127 (no atomics)
        float breg[8];
        #pragma unroll
        for (int jj = 0; jj < 8; ++jj) breg[jj] = ldf(bfP, tj + 16 * jj, m);
        #pragma unroll
        for (int i = 0; i < 2; ++i) {
            float* aout = &A[(eb + i) * LDA];
            #pragma unroll
            for (int jj = 0; jj < 8; ++jj) {
                int col = tj + 16 * jj;
                aout[col] = silu_f(acc[i][jj] + breg[jj]);
            }
        }
        __syncthreads();
        // stage Wg [128][16] -> Bs[0..2047]
        if (m) {
            const float* Wg = (const float*)WgP;
            for (int i = t; i < 2048; i += 256) Bs[i] = Wg[i];
        } else {
            const unsigned short* Wg = (const unsigned short*)WgP;
            for (int i = t; i < 2048; i += 256) Bs[i] = bf2f(Wg[i]);
        }
        __syncthreads();
        // gates[e][o] = sigmoid(feats @ Wg + bg)
        for (int r = 0; r < 2; ++r) {
            int idx = t + 256 * r;
            int e = idx / 16, o = idx % 16;
            const float* fe = &A[e * LDA];
            float g = ldf(bgP, o, m);
            for (int j = 0; j < S_DIM; ++j)
                g += fe[j] * Bs[j * 16 + o];
            gates[idx] = sigm_f(g);
        }
        __syncthreads();
        // mv -> Bs[e*48+oc]
        for (int r = 0; r < 6; ++r) {
            int idx = t + 256 * r;
            int e = idx / 48, oc = idx % 48, o = oc / 3;
            Bs[e * 48 + oc] = vureg[r] * gates[e * 16 + o];
        }
        __syncthreads();
        // run-flush accumulate into LDS agg (single writer per column c)
        if (t < 176) {
            int c = t;
            float racc = 0.f;
            for (int e = 0; e < cnt; ++e) {
                racc += (c < 128) ? A[e * LDA + c] : Bs[e * 48 + (c - 128)];
                bool flush = (e == cnt - 1) || (dstb[e + 1] != dstb[e]);
                if (flush) {
                    agg[dstb[e] * 176 + c] += racc;
                    racc = 0.f;
                }
            }
        }
        __syncthreads();   // before next tile overwrites A/Bs/srcb/dstb
    }
    // write agg once, plain coalesced stores (exclusive ownership)
    for (int idx = t; idx < DPB * 176; idx += 256) {
        int d = idx / 176, c = idx % 176;
        int n = d0 + d;
        if (c < 128) agg_s[(size_t)n * 128 + c] = agg[idx];
        else         agg_v[(size_t)n * 48 + (c - 128)] = agg[idx];
    }
}

// ---------------------------------------------------------------------------
// Node (update) kernel: per block, 32 nodes. Update GVP + residual + LN.
// ---------------------------------------------------------------------------
__global__ __launch_bounds__(256) void node_kernel(
    const void* sP, const void* vP,
    const void* WhP, const void* WuP, const void* WfP,
    const void* bfP, const void* WgP, const void* bgP,
    const void* lngP, const void* lnbP,
    const int* __restrict__ flagp,
    const float* __restrict__ agg_s,         // [N][128]
    const float* __restrict__ agg_v,         // [N][48]
    void* outP)                              // [N*128] then [N*48]
{
    __shared__ float A2[NB * LDA2];
    __shared__ float Bs2[4096];
    __shared__ float WhWu2[HU * 16];
    __shared__ float gates2[NB * 16];
    __shared__ float WhS[HU * HU];
    __shared__ float mu_s[NB], rstd_s[NB], vn_s[NB];

    const int t = threadIdx.x;
    const int n0 = blockIdx.x * NB;
    const int m = flagp[0];

    if (m) {
        const float* Wh = (const float*)WhP;
        const float* Wu = (const float*)WuP;
        for (int i = t; i < HU * HU; i += 256) WhS[i] = Wh[i];
        for (int i = t; i < HU * 16; i += 256) gates2[i] = Wu[i];
    } else {
        const unsigned short* Wh = (const unsigned short*)WhP;
        const unsigned short* Wu = (const unsigned short*)WuP;
        for (int i = t; i < HU * HU; i += 256) WhS[i] = bf2f(Wh[i]);
        for (int i = t; i < HU * 16; i += 256) gates2[i] = bf2f(Wu[i]);
    }
    if (m) {
        const float* sF = (const float*)sP;
        for (int idx = t; idx < NB * 32; idx += 256) {
            int ni = idx >> 5, col4 = (idx & 31) * 4;
            int n = n0 + ni;
            float* a = &A2[ni * LDA2 + col4];
            if (n < N_NODES) {
                float4 u = *(const float4*)(sF + (size_t)n * 128 + col4);
                a[0] = u.x; a[1] = u.y; a[2] = u.z; a[3] = u.w;
            } else { a[0] = a[1] = a[2] = a[3] = 0.f; }
        }
    } else {
        const unsigned short* sU = (const unsigned short*)sP;
        for (int idx = t; idx < NB * 32; idx += 256) {
            int ni = idx >> 5, col4 = (idx & 31) * 4;
            int n = n0 + ni;
            float* a = &A2[ni * LDA2 + col4];
            if (n < N_NODES) {
                ushort4 u = *(const ushort4*)(sU + (size_t)n * 128 + col4);
                a[0] = bf2f(u.x); a[1] = bf2f(u.y); a[2] = bf2f(u.z); a[3] = bf2f(u.w);
            } else { a[0] = a[1] = a[2] = a[3] = 0.f; }
        }
    }
    for (int idx = t; idx < NB * 32; idx += 256) {
        int ni = idx >> 5, col4 = (idx & 31) * 4;
        int n = n0 + ni;
        float* a = &A2[ni * LDA2 + 128 + col4];
        if (n < N_NODES) {
            float4 u = *(const float4*)(agg_s + (size_t)n * 128 + col4);
            a[0] = u.x * 0.1f; a[1] = u.y * 0.1f; a[2] = u.z * 0.1f; a[3] = u.w * 0.1f;
        } else { a[0] = a[1] = a[2] = a[3] = 0.f; }
    }
    for (int idx = t; idx < NB * 96; idx += 256) {
        int ni = idx / 96, vc = idx % 96;
        int n = n0 + ni;
        float val = 0.f;
        if (n < N_NODES)
            val = (vc < 48) ? ldf(vP, n * 48 + vc, m)
                            : agg_v[(size_t)n * 48 + (vc - 48)] * 0.1f;
        Bs2[ni * 100 + vc] = val;
    }
    __syncthreads();
    for (int idx = t; idx < HU * 16; idx += 256) {
        int vv = idx / 16, o = idx % 16;
        float acc = 0.f;
        for (int h = 0; h < HU; ++h)
            acc += WhS[vv * HU + h] * gates2[h * 16 + o];
        WhWu2[idx] = acc;
    }
    for (int idx = t; idx < NB * HU; idx += 256) {
        int ni = idx / HU, h = idx % HU;
        const float* vc = &Bs2[ni * 100];
        float vh0 = 0.f, vh1 = 0.f, vh2 = 0.f;
        for (int vv = 0; vv < HU; ++vv) {
            float w = WhS[vv * HU + h];
            vh0 += vc[vv * 3 + 0] * w; vh1 += vc[vv * 3 + 1] * w; vh2 += vc[vv * 3 + 2] * w;
        }
        A2[ni * LDA2 + 256 + h] = sqrtf(fmaxf(vh0 * vh0 + vh1 * vh1 + vh2 * vh2, 1e-8f));
    }
    __syncthreads();
    float vureg[6];
    for (int r = 0; r < 6; ++r) {
        int idx = t + 256 * r;
        int ni = idx / 48, oc = idx % 48, o = oc / 3, c = oc % 3;
        const float* vc = &Bs2[ni * 100];
        float acc = 0.f;
        for (int vv = 0; vv < HU; ++vv)
            acc += vc[vv * 3 + c] * WhWu2[vv * 16 + o];
        vureg[r] = acc;
    }
    __syncthreads();

    const int tj = t & 15, tn = t >> 4;
    const int nb = tn * 2;
    float acc[2][8];
    #pragma unroll
    for (int i = 0; i < 2; ++i)
        #pragma unroll
        for (int j = 0; j < 8; ++j) acc[i][j] = 0.f;

    for (int kk = 0; kk < KU; kk += 32) {
        if (m) {
            const float* WfF = (const float*)WfP;
            for (int idx = t; idx < 32 * 32; idx += 256) {
                int kt = idx >> 5, col4 = (idx & 31) * 4;
                float4 u = *(const float4*)(WfF + (size_t)(kk + kt) * 128 + col4);
                float* b = &Bs2[kt * 128 + col4];
                b[0] = u.x; b[1] = u.y; b[2] = u.z; b[3] = u.w;
            }
        } else {
            const unsigned short* WfU = (const unsigned short*)WfP;
            for (int idx = t; idx < 32 * 32; idx += 256) {
                int kt = idx >> 5, col4 = (idx & 31) * 4;
                ushort4 u = *(const ushort4*)(WfU + (size_t)(kk + kt) * 128 + col4);
                float* b = &Bs2[kt * 128 + col4];
                b[0] = bf2f(u.x); b[1] = bf2f(u.y); b[2] = bf2f(u.z); b[3] = bf2f(u.w);
            }
        }
        __syncthreads();
        for (int kt = 0; kt < 32; ++kt) {
            float a0 = A2[(nb + 0) * LDA2 + kk + kt];
            float a1 = A2[(nb + 1) * LDA2 + kk + kt];
            const float* brow = &Bs2[kt * 128 + tj];
            #pragma unroll
            for (int jj = 0; jj < 8; ++jj) {
                float b = brow[16 * jj];
                acc[0][jj] += a0 * b; acc[1][jj] += a1 * b;
            }
        }
        __syncthreads();
    }
    float breg[8];
    #pragma unroll
    for (int jj = 0; jj < 8; ++jj) breg[jj] = ldf(bfP, tj + 16 * jj, m);
    #pragma unroll
    for (int i = 0; i < 2; ++i) {
        float* aout = &A2[(nb + i) * LDA2 + 128];
        #pragma unroll
        for (int jj = 0; jj < 8; ++jj) {
            int col = tj + 16 * jj;
            aout[col] = silu_f(acc[i][jj] + breg[jj]);
        }
    }
    __syncthreads();
    if (m) {
        const float* Wg = (const float*)WgP;
        for (int i = t; i < 2048; i += 256) Bs2[i] = Wg[i];
    } else {
        const unsigned short* Wg = (const unsigned short*)WgP;
        for (int i = t; i < 2048; i += 256) Bs2[i] = bf2f(Wg[i]);
    }
    __syncthreads();
    for (int r = 0; r < 2; ++r) {
        int idx = t + 256 * r;
        int ni = idx / 16, o = idx % 16;
        const float* fe = &A2[ni * LDA2 + 128];
        float g = ldf(bgP, o, m);
        for (int j = 0; j < 128; ++j)
            g += fe[j] * Bs2[j * 16 + o];
        gates2[idx] = sigm_f(g);
    }
    __syncthreads();
    for (int r = 0; r < 6; ++r) {
        int idx = t + 256 * r;
        int ni = idx / 48, oc = idx % 48, o = oc / 3;
        int n = n0 + ni;
        float vres = 0.f;
        if (n < N_NODES)
            vres = ldf(vP, n * 48 + oc, m) + vureg[r] * gates2[ni * 16 + o];
        Bs2[ni * 48 + oc] = vres;
    }
    __syncthreads();
    if (t < NB) {
        const float* arow = &A2[t * LDA2];
        float sum = 0.f, sumsq = 0.f;
        for (int j = 0; j < 128; ++j) {
            float xr = arow[j] + arow[128 + j];
            sum += xr; sumsq += xr * xr;
        }
        float mu = sum * (1.f / 128.f);
        float var = sumsq * (1.f / 128.f) - mu * mu;
        mu_s[t] = mu;
        rstd_s[t] = rsqrtf(fmaxf(var, 0.f) + 1e-5f);
        const float* vr = &Bs2[t * 48];
        float accv = 0.f;
        for (int o = 0; o < 16; ++o) {
            float mm = vr[o*3]*vr[o*3] + vr[o*3+1]*vr[o*3+1] + vr[o*3+2]*vr[o*3+2];
            accv += fmaxf(mm, 1e-8f);
        }
        vn_s[t] = sqrtf(accv * (1.f / 16.f) + 1e-5f) + 1e-5f;
    }
    __syncthreads();
    float* outF = (float*)outP;
    unsigned short* outU = (unsigned short*)outP;
    for (int idx = t; idx < NB * 128; idx += 256) {
        int ni = idx >> 7, j = idx & 127;
        int n = n0 + ni;
        if (n < N_NODES) {
            float xr = A2[ni * LDA2 + j] + A2[ni * LDA2 + 128 + j];
            float o = (xr - mu_s[ni]) * rstd_s[ni] * ldf(lngP, j, m) + ldf(lnbP, j, m);
            if (m) outF[(size_t)n * 128 + j] = o;
            else   outU[(size_t)n * 128 + j] = f2bf(o);
        }
    }
    for (int idx = t; idx < NB * 48; idx += 256) {
        int ni = idx / 48, oc = idx % 48;
        int n = n0 + ni;
        if (n < N_NODES) {
            float o = Bs2[ni * 48 + oc] / vn_s[ni];
            if (m) outF[(size_t)N_NODES * 128 + (size_t)n * 48 + oc] = o;
            else   outU[(size_t)N_NODES * 128 + (size_t)n * 48 + oc] = f2bf(o);
        }
    }
}

extern "C" void kernel_launch(void* const* d_in, const int* in_sizes, int n_in,
                              void* d_out, int out_size, void* d_ws, size_t ws_size,
                              hipStream_t stream) {
    const int* ei = (const int*)d_in[17];

    // ws layout: flag(64B) | deg[N] | cursor[N] | row_ptr[N] | ssrc[E] | sdst[E]
    //            | agg_s[N*128] | agg_v[N*48]
    char* base = (char*)d_ws;
    int*   flag    = (int*)base;
    int*   deg     = (int*)(base + 64);
    int*   cursor  = deg + N_NODES;
    int*   row_ptr = cursor + N_NODES;
    int*   ssrc    = row_ptr + N_NODES;
    int*   sdst    = ssrc + E_EDGES;
    float* agg_s   = (float*)(sdst + E_EDGES);
    float* agg_v   = agg_s + (size_t)N_NODES * 128;

    // zero only flag + deg; agg is fully overwritten by edge_kernel stores
    hipMemsetAsync(d_ws, 0, 64 + (size_t)N_NODES * 4, stream);

    detect_kernel<<<1, 64, 0, stream>>>((const unsigned short*)d_in[0], flag);
    hist_kernel<<<(E_EDGES + 255) / 256, 256, 0, stream>>>(ei, deg);
    scan_kernel<<<1, 1024, 0, stream>>>(deg, cursor, row_ptr);
    scatter_kernel<<<(E_EDGES + 255) / 256, 256, 0, stream>>>(ei, cursor, ssrc, sdst);

    edge_kernel<<<N_NODES / DPB, 256, 0, stream>>>(
        d_in[0], d_in[1], d_in[2], d_in[3], d_in[4], d_in[5],
        d_in[6], d_in[7], d_in[8], row_ptr, ssrc, sdst, flag, agg_s, agg_v);
    node_kernel<<<(N_NODES + NB - 1) / NB, 256, 0, stream>>>(
        d_in[0], d_in[1], d_in[9], d_in[10], d_in[11], d_in[12],
        d_in[13], d_in[14], d_in[15], d_in[16], flag,
        agg_s, agg_v, (void*)d_out);
}

// Round 7
// 3624.783 us; speedup vs baseline: 1.0663x; 1.0663x over previous
//
#include <hip/hip_runtime.h>
#include <hip/hip_bf16.h>
#include <math.h>

#define N_NODES 50000
#define E_EDGES 800000
#define S_DIM 128
#define V_DIM 16
#define HM 17            // message GVP dim_h / vectors-in
#define KM 161           // 128 + 16 rbf + 17 sh
#define HU 32            // update GVP vectors-in
#define KU 288           // 256 + 32 sh

#define EB 32            // edges per tile
#define DPG 8            // dst nodes per agg-group
#define NGRP 2           // agg-groups per block -> 16 nodes/block
#define NB 32            // nodes per block (node kernel)
#define LDA2 292         // node A-tile leading dim (288 used)

__device__ __forceinline__ float bf2f(unsigned short u) {
    union { unsigned int i; float f; } w; w.i = ((unsigned int)u) << 16; return w.f;
}
__device__ __forceinline__ unsigned short f2bf(float f) {
    union { float f; unsigned int i; } w; w.f = f;
    unsigned int x = w.i;
    x += 0x7fff + ((x >> 16) & 1);
    return (unsigned short)(x >> 16);
}
__device__ __forceinline__ float silu_f(float x) { return x / (1.f + __expf(-x)); }
__device__ __forceinline__ float sigm_f(float x) { return 1.f / (1.f + __expf(-x)); }
__device__ __forceinline__ float ldf(const void* p, int i, int m) {
    if (m) return ((const float*)p)[i];
    return bf2f(((const unsigned short*)p)[i]);
}

// ---------------------------------------------------------------------------
// Detector: fp32 (flag=1) vs bf16 (flag=0) float inputs.
// ---------------------------------------------------------------------------
__global__ void detect_kernel(const unsigned short* __restrict__ s_us,
                              int* __restrict__ flag) {
    int t = threadIdx.x;
    int huge = 0;
    for (int k = 0; k < 16; ++k) {
        unsigned short u = s_us[2 * (t + 64 * k)];
        int e = (u >> 7) & 0xFF;
        if (e > 140) huge = 1;
    }
    if (huge) atomicOr(flag, 1);
}

// ---------------------------------------------------------------------------
// CSR build: histogram -> exclusive scan -> scatter.
// ---------------------------------------------------------------------------
__global__ __launch_bounds__(256) void hist_kernel(const int* __restrict__ ei,
                                                   int* __restrict__ deg) {
    int e = blockIdx.x * 256 + threadIdx.x;
    if (e < E_EDGES) atomicAdd(&deg[ei[E_EDGES + e]], 1);
}

__global__ __launch_bounds__(1024) void scan_kernel(const int* __restrict__ deg,
                                                    int* __restrict__ cursor,
                                                    int* __restrict__ row_ptr) {
    __shared__ int part[1024];
    const int t = threadIdx.x;
    const int CH = 49;                      // 1024*49 >= 50000
    int base = t * CH;
    int s = 0;
    for (int i = 0; i < CH; ++i) {
        int idx = base + i;
        if (idx < N_NODES) s += deg[idx];
    }
    part[t] = s;
    __syncthreads();
    if (t == 0) {
        int run = 0;
        for (int i = 0; i < 1024; ++i) { int tmp = part[i]; part[i] = run; run += tmp; }
    }
    __syncthreads();
    int run = part[t];
    for (int i = 0; i < CH; ++i) {
        int idx = base + i;
        if (idx < N_NODES) { cursor[idx] = run; row_ptr[idx] = run; run += deg[idx]; }
    }
}

__global__ __launch_bounds__(256) void scatter_kernel(const int* __restrict__ ei,
                                                      int* __restrict__ cursor,
                                                      int* __restrict__ ssrc,
                                                      int* __restrict__ sdst) {
    int e = blockIdx.x * 256 + threadIdx.x;
    if (e >= E_EDGES) return;
    int src = ei[e], dst = ei[E_EDGES + e];
    int pos = atomicAdd(&cursor[dst], 1);
    ssrc[pos] = src;
    sdst[pos] = dst;
}

// ---------------------------------------------------------------------------
// Edge kernel: block owns 16 dst nodes (2 groups of 8), CSR edges in 32-edge
// tiles. Wf/Wg staged ONCE per block in LDS as packed-bf16 pairs (u32) ->
// no per-tile weight restaging, no mid-GEMM barriers. Zero global atomics.
// LDS ~80.6 KB -> 2 blocks/CU.
// ---------------------------------------------------------------------------
__global__ __launch_bounds__(256, 2) void edge_kernel(
    const void* sP, const void* vP, const void* xP,
    const void* WhP, const void* WuP, const void* WfP,
    const void* bfP, const void* WgP, const void* bgP,
    const int* __restrict__ row_ptr,
    const int* __restrict__ ssrc,
    const int* __restrict__ sdst,
    const int* __restrict__ flagp,
    float* __restrict__ agg_s,               // [N][128]
    float* __restrict__ agg_v)               // [N][48]
{
    __shared__ unsigned int WfS[KM * 64];    // 41216 B: packed bf16 col-pairs
    __shared__ float A[EB * KM];             // 20608 B: 0..127 s->feats, 128..143 rbf->gates, 144..160 sh
    __shared__ float vinB[EB * 51];          // 6528 B: vin (48 v + 3 unit) -> mv[32][48]; Wu scratch early
    __shared__ unsigned int WgS[128 * 8];    // 4096 B: packed bf16 pairs
    __shared__ float WhWu[HM * 16];          // 1088 B
    __shared__ float WhS[HM * HM];           // 1156 B
    __shared__ float agg[DPG * 176];         // 5632 B
    __shared__ int srcb[EB], dstb[EB];       // 256 B

    const int t = threadIdx.x;
    const int m = flagp[0];                  // 1 = fp32 inputs
    const int d0 = blockIdx.x * (DPG * NGRP);

    // ---- block-once staging ----
    if (m) {
        const float* Wh = (const float*)WhP;
        const float* Wu = (const float*)WuP;
        for (int i = t; i < HM * HM; i += 256) WhS[i] = Wh[i];
        for (int i = t; i < HM * 16; i += 256) vinB[i] = Wu[i];   // scratch
    } else {
        const unsigned short* Wh = (const unsigned short*)WhP;
        const unsigned short* Wu = (const unsigned short*)WuP;
        for (int i = t; i < HM * HM; i += 256) WhS[i] = bf2f(Wh[i]);
        for (int i = t; i < HM * 16; i += 256) vinB[i] = bf2f(Wu[i]);
    }
    for (int idx = t; idx < KM * 64; idx += 256) {       // Wf -> packed bf16
        int kt = idx >> 6, p = idx & 63;
        float w0 = ldf(WfP, kt * 128 + 2 * p, m);
        float w1 = ldf(WfP, kt * 128 + 2 * p + 1, m);
        WfS[idx] = (unsigned int)f2bf(w0) | ((unsigned int)f2bf(w1) << 16);
    }
    for (int idx = t; idx < 128 * 8; idx += 256) {       // Wg -> packed bf16
        int j = idx >> 3, p = idx & 7;
        float w0 = ldf(WgP, j * 16 + 2 * p, m);
        float w1 = ldf(WgP, j * 16 + 2 * p + 1, m);
        WgS[idx] = (unsigned int)f2bf(w0) | ((unsigned int)f2bf(w1) << 16);
    }
    __syncthreads();
    for (int idx = t; idx < HM * 16; idx += 256) {       // WhWu = Wh @ Wu
        int vv = idx / 16, o = idx % 16;
        float acc = 0.f;
        for (int h = 0; h < HM; ++h)
            acc += WhS[vv * HM + h] * vinB[h * 16 + o];
        WhWu[idx] = acc;
    }
    __syncthreads();                                     // vinB scratch free

    const int tj = t & 15, te = t >> 4;
    const int eb = te * 2;
    float breg[8];
    #pragma unroll
    for (int jj = 0; jj < 4; ++jj) {
        breg[2 * jj]     = ldf(bfP, 2 * tj + 32 * jj, m);
        breg[2 * jj + 1] = ldf(bfP, 2 * tj + 32 * jj + 1, m);
    }
    const int go = t & 15;                               // gates o (same both r-iters)
    const float bg_r = ldf(bgP, go, m);
    const bool g_odd = (go & 1);
    const int g_p = go >> 1;

    for (int g = 0; g < NGRP; ++g) {
        const int dg = d0 + g * DPG;
        const int e_beg = row_ptr[dg];
        const int e_end = (dg + DPG >= N_NODES) ? E_EDGES : row_ptr[dg + DPG];
        for (int i = t; i < DPG * 176; i += 256) agg[i] = 0.f;
        __syncthreads();

        for (int et = e_beg; et < e_end; et += EB) {
            const int cnt = min(EB, e_end - et);
            if (t < EB) {
                srcb[t] = (t < cnt) ? ssrc[et + t] : 0;
                dstb[t] = (t < cnt) ? (sdst[et + t] - dg) : 0;
            }
            __syncthreads();
            // s-gather into A cols 0..127
            {
                int cj = t & 31, ce = t >> 5;
                if (m) {
                    const float* sF = (const float*)sP;
                    for (int r = 0; r < 4; ++r) {
                        int e = ce + 8 * r;
                        float4 u = *(const float4*)(sF + (size_t)srcb[e] * S_DIM + cj * 4);
                        float* a = &A[e * KM + cj * 4];
                        a[0] = u.x; a[1] = u.y; a[2] = u.z; a[3] = u.w;
                    }
                } else {
                    const unsigned short* sU = (const unsigned short*)sP;
                    for (int r = 0; r < 4; ++r) {
                        int e = ce + 8 * r;
                        ushort4 u = *(const ushort4*)(sU + (size_t)srcb[e] * S_DIM + cj * 4);
                        float* a = &A[e * KM + cj * 4];
                        a[0] = bf2f(u.x); a[1] = bf2f(u.y); a[2] = bf2f(u.z); a[3] = bf2f(u.w);
                    }
                }
            }
            // vin + geometry/rbf
            if (t < 128) {
                int e = t >> 2, q = t & 3;
                int src = srcb[e];
                float* vin = &vinB[e * 51 + q * 12];
                if (m) {
                    const float* vp = (const float*)vP + (size_t)src * 48 + q * 12;
                    for (int i = 0; i < 3; ++i) {
                        float4 u = *(const float4*)(vp + i * 4);
                        vin[i * 4 + 0] = u.x; vin[i * 4 + 1] = u.y;
                        vin[i * 4 + 2] = u.z; vin[i * 4 + 3] = u.w;
                    }
                } else {
                    const unsigned short* vp = (const unsigned short*)vP + (size_t)src * 48 + q * 12;
                    for (int i = 0; i < 3; ++i) {
                        ushort4 u = *(const ushort4*)(vp + i * 4);
                        vin[i * 4 + 0] = bf2f(u.x); vin[i * 4 + 1] = bf2f(u.y);
                        vin[i * 4 + 2] = bf2f(u.z); vin[i * 4 + 3] = bf2f(u.w);
                    }
                }
                if (q == 0) {
                    int dst = dg + dstb[e];
                    float dxc[3]; float d2 = 0.f;
                    for (int c = 0; c < 3; ++c) {
                        float xs = ldf(xP, src * 3 + c, m);
                        float xd = ldf(xP, dst * 3 + c, m);
                        dxc[c] = xd - xs; d2 += dxc[c] * dxc[c];
                    }
                    float dist = sqrtf(fmaxf(d2, 1e-8f));
                    float inv = 1.f / dist;
                    for (int c = 0; c < 3; ++c) vinB[e * 51 + 48 + c] = dxc[c] * inv;
                    for (int k = 0; k < 16; ++k) {
                        float mu = (20.f / 15.f) * (float)k;
                        float z = (dist - mu) * (1.f / 1.25f);
                        A[e * KM + 128 + k] = __expf(-z * z);
                    }
                }
            }
            __syncthreads();
            // sh -> A cols 144..160
            for (int idx = t; idx < EB * HM; idx += 256) {
                int e = idx / HM, h = idx % HM;
                const float* vin = &vinB[e * 51];
                float vh0 = 0.f, vh1 = 0.f, vh2 = 0.f;
                for (int vv = 0; vv < HM; ++vv) {
                    float w = WhS[vv * HM + h];
                    vh0 += vin[vv * 3 + 0] * w;
                    vh1 += vin[vv * 3 + 1] * w;
                    vh2 += vin[vv * 3 + 2] * w;
                }
                A[e * KM + 144 + h] = sqrtf(fmaxf(vh0 * vh0 + vh1 * vh1 + vh2 * vh2, 1e-8f));
            }
            // Vu into registers
            float vureg[6];
            for (int r = 0; r < 6; ++r) {
                int idx = t + 256 * r;
                int e = idx / 48, oc = idx % 48, o = oc / 3, c = oc % 3;
                const float* vin = &vinB[e * 51];
                float acc = 0.f;
                for (int vv = 0; vv < HM; ++vv)
                    acc += vin[vv * 3 + c] * WhWu[vv * 16 + o];
                vureg[r] = acc;
            }
            __syncthreads();

            // GEMM feats[32][128] = A[32][161] @ Wf (LDS-resident, packed bf16)
            // thread: edges eb,eb+1; cols {2*tj + 32*jj + d}
            float acc[2][8];
            #pragma unroll
            for (int i = 0; i < 2; ++i)
                #pragma unroll
                for (int j = 0; j < 8; ++j) acc[i][j] = 0.f;
            for (int kt = 0; kt < KM; ++kt) {
                float a0 = A[(eb + 0) * KM + kt];
                float a1 = A[(eb + 1) * KM + kt];
                const unsigned int* wrow = &WfS[kt * 64 + tj];
                #pragma unroll
                for (int jj = 0; jj < 4; ++jj) {
                    unsigned int u = wrow[16 * jj];
                    union { unsigned int i; float f; } lo, hi;
                    lo.i = u << 16;
                    hi.i = u & 0xFFFF0000u;
                    acc[0][2 * jj]     += a0 * lo.f;
                    acc[0][2 * jj + 1] += a0 * hi.f;
                    acc[1][2 * jj]     += a1 * lo.f;
                    acc[1][2 * jj + 1] += a1 * hi.f;
                }
            }
            __syncthreads();   // A reads done before feats overwrite
            #pragma unroll
            for (int i = 0; i < 2; ++i) {
                float* aout = &A[(eb + i) * KM];
                #pragma unroll
                for (int jj = 0; jj < 4; ++jj) {
                    aout[2 * tj + 32 * jj]     = silu_f(acc[i][2 * jj] + breg[2 * jj]);
                    aout[2 * tj + 32 * jj + 1] = silu_f(acc[i][2 * jj + 1] + breg[2 * jj + 1]);
                }
            }
            __syncthreads();
            // gates -> A cols 128..143 (rbf zone, dead)
            for (int r = 0; r < 2; ++r) {
                int e = (t + 256 * r) >> 4;
                const float* fe = &A[e * KM];
                float gv = bg_r;
                for (int j = 0; j < 128; ++j) {
                    unsigned int u = WgS[j * 8 + g_p];
                    union { unsigned int i; float f; } w;
                    w.i = g_odd ? (u & 0xFFFF0000u) : (u << 16);
                    gv += fe[j] * w.f;
                }
                A[e * KM + 128 + go] = sigm_f(gv);
            }
            __syncthreads();
            // mv -> vinB[e*48+oc]
            for (int r = 0; r < 6; ++r) {
                int idx = t + 256 * r;
                int e = idx / 48, oc = idx % 48, o = oc / 3;
                vinB[e * 48 + oc] = vureg[r] * A[e * KM + 128 + o];
            }
            __syncthreads();
            // run-flush into agg (single writer per column)
            if (t < 176) {
                int c = t;
                float racc = 0.f;
                for (int e = 0; e < cnt; ++e) {
                    racc += (c < 128) ? A[e * KM + c] : vinB[e * 48 + (c - 128)];
                    bool flush = (e == cnt - 1) || (dstb[e + 1] != dstb[e]);
                    if (flush) { agg[dstb[e] * 176 + c] += racc; racc = 0.f; }
                }
            }
            __syncthreads();
        }
        // store group agg (plain coalesced stores, exclusive ownership)
        for (int idx = t; idx < DPG * 176; idx += 256) {
            int d = idx / 176, c = idx % 176;
            int n = dg + d;
            if (c < 128) agg_s[(size_t)n * 128 + c] = agg[idx];
            else         agg_v[(size_t)n * 48 + (c - 128)] = agg[idx];
        }
        __syncthreads();
    }
}

// ---------------------------------------------------------------------------
// Node (update) kernel: per block, 32 nodes. Update GVP + residual + LN.
// ---------------------------------------------------------------------------
__global__ __launch_bounds__(256) void node_kernel(
    const void* sP, const void* vP,
    const void* WhP, const void* WuP, const void* WfP,
    const void* bfP, const void* WgP, const void* bgP,
    const void* lngP, const void* lnbP,
    const int* __restrict__ flagp,
    const float* __restrict__ agg_s,         // [N][128]
    const float* __restrict__ agg_v,         // [N][48]
    void* outP)                              // [N*128] then [N*48]
{
    __shared__ float A2[NB * LDA2];
    __shared__ float Bs2[4096];
    __shared__ float WhWu2[HU * 16];
    __shared__ float gates2[NB * 16];
    __shared__ float WhS[HU * HU];
    __shared__ float mu_s[NB], rstd_s[NB], vn_s[NB];

    const int t = threadIdx.x;
    const int n0 = blockIdx.x * NB;
    const int m = flagp[0];

    if (m) {
        const float* Wh = (const float*)WhP;
        const float* Wu = (const float*)WuP;
        for (int i = t; i < HU * HU; i += 256) WhS[i] = Wh[i];
        for (int i = t; i < HU * 16; i += 256) gates2[i] = Wu[i];
    } else {
        const unsigned short* Wh = (const unsigned short*)WhP;
        const unsigned short* Wu = (const unsigned short*)WuP;
        for (int i = t; i < HU * HU; i += 256) WhS[i] = bf2f(Wh[i]);
        for (int i = t; i < HU * 16; i += 256) gates2[i] = bf2f(Wu[i]);
    }
    if (m) {
        const float* sF = (const float*)sP;
        for (int idx = t; idx < NB * 32; idx += 256) {
            int ni = idx >> 5, col4 = (idx & 31) * 4;
            int n = n0 + ni;
            float* a = &A2[ni * LDA2 + col4];
            if (n < N_NODES) {
                float4 u = *(const float4*)(sF + (size_t)n * 128 + col4);
                a[0] = u.x; a[1] = u.y; a[2] = u.z; a[3] = u.w;
            } else { a[0] = a[1] = a[2] = a[3] = 0.f; }
        }
    } else {
        const unsigned short* sU = (const unsigned short*)sP;
        for (int idx = t; idx < NB * 32; idx += 256) {
            int ni = idx >> 5, col4 = (idx & 31) * 4;
            int n = n0 + ni;
            float* a = &A2[ni * LDA2 + col4];
            if (n < N_NODES) {
                ushort4 u = *(const ushort4*)(sU + (size_t)n * 128 + col4);
                a[0] = bf2f(u.x); a[1] = bf2f(u.y); a[2] = bf2f(u.z); a[3] = bf2f(u.w);
            } else { a[0] = a[1] = a[2] = a[3] = 0.f; }
        }
    }
    for (int idx = t; idx < NB * 32; idx += 256) {
        int ni = idx >> 5, col4 = (idx & 31) * 4;
        int n = n0 + ni;
        float* a = &A2[ni * LDA2 + 128 + col4];
        if (n < N_NODES) {
            float4 u = *(const float4*)(agg_s + (size_t)n * 128 + col4);
            a[0] = u.x * 0.1f; a[1] = u.y * 0.1f; a[2] = u.z * 0.1f; a[3] = u.w * 0.1f;
        } else { a[0] = a[1] = a[2] = a[3] = 0.f; }
    }
    for (int idx = t; idx < NB * 96; idx += 256) {
        int ni = idx / 96, vc = idx % 96;
        int n = n0 + ni;
        float val = 0.f;
        if (n < N_NODES)
            val = (vc < 48) ? ldf(vP, n * 48 + vc, m)
                            : agg_v[(size_t)n * 48 + (vc - 48)] * 0.1f;
        Bs2[ni * 100 + vc] = val;
    }
    __syncthreads();
    for (int idx = t; idx < HU * 16; idx += 256) {
        int vv = idx / 16, o = idx % 16;
        float acc = 0.f;
        for (int h = 0; h < HU; ++h)
            acc += WhS[vv * HU + h] * gates2[h * 16 + o];
        WhWu2[idx] = acc;
    }
    for (int idx = t; idx < NB * HU; idx += 256) {
        int ni = idx / HU, h = idx % HU;
        const float* vc = &Bs2[ni * 100];
        float vh0 = 0.f, vh1 = 0.f, vh2 = 0.f;
        for (int vv = 0; vv < HU; ++vv) {
            float w = WhS[vv * HU + h];
            vh0 += vc[vv * 3 + 0] * w; vh1 += vc[vv * 3 + 1] * w; vh2 += vc[vv * 3 + 2] * w;
        }
        A2[ni * LDA2 + 256 + h] = sqrtf(fmaxf(vh0 * vh0 + vh1 * vh1 + vh2 * vh2, 1e-8f));
    }
    __syncthreads();
    float vureg[6];
    for (int r = 0; r < 6; ++r) {
        int idx = t + 256 * r;
        int ni = idx / 48, oc = idx % 48, o = oc / 3, c = oc % 3;
        const float* vc = &Bs2[ni * 100];
        float acc = 0.f;
        for (int vv = 0; vv < HU; ++vv)
            acc += vc[vv * 3 + c] * WhWu2[vv * 16 + o];
        vureg[r] = acc;
    }
    __syncthreads();

    const int tj = t & 15, tn = t >> 4;
    const int nb = tn * 2;
    float acc[2][8];
    #pragma unroll
    for (int i = 0; i < 2; ++i)
        #pragma unroll
        for (int j = 0; j < 8; ++j) acc[i][j] = 0.f;

    for (int kk = 0; kk < KU; kk += 32) {
        if (m) {
            const float* WfF = (const float*)WfP;
            for (int idx = t; idx < 32 * 32; idx += 256) {
                int kt = idx >> 5, col4 = (idx & 31) * 4;
                float4 u = *(const float4*)(WfF + (size_t)(kk + kt) * 128 + col4);
                float* b = &Bs2[kt * 128 + col4];
                b[0] = u.x; b[1] = u.y; b[2] = u.z; b[3] = u.w;
            }
        } else {
            const unsigned short* WfU = (const unsigned short*)WfP;
            for (int idx = t; idx < 32 * 32; idx += 256) {
                int kt = idx >> 5, col4 = (idx & 31) * 4;
                ushort4 u = *(const ushort4*)(WfU + (size_t)(kk + kt) * 128 + col4);
                float* b = &Bs2[kt * 128 + col4];
                b[0] = bf2f(u.x); b[1] = bf2f(u.y); b[2] = bf2f(u.z); b[3] = bf2f(u.w);
            }
        }
        __syncthreads();
        for (int kt = 0; kt < 32; ++kt) {
            float a0 = A2[(nb + 0) * LDA2 + kk + kt];
            float a1 = A2[(nb + 1) * LDA2 + kk + kt];
            const float* brow = &Bs2[kt * 128 + tj];
            #pragma unroll
            for (int jj = 0; jj < 8; ++jj) {
                float b = brow[16 * jj];
                acc[0][jj] += a0 * b; acc[1][jj] += a1 * b;
            }
        }
        __syncthreads();
    }
    float breg[8];
    #pragma unroll
    for (int jj = 0; jj < 8; ++jj) breg[jj] = ldf(bfP, tj + 16 * jj, m);
    #pragma unroll
    for (int i = 0; i < 2; ++i) {
        float* aout = &A2[(nb + i) * LDA2 + 128];
        #pragma unroll
        for (int jj = 0; jj < 8; ++jj) {
            int col = tj + 16 * jj;
            aout[col] = silu_f(acc[i][jj] + breg[jj]);
        }
    }
    __syncthreads();
    if (m) {
        const float* Wg = (const float*)WgP;
        for (int i = t; i < 2048; i += 256) Bs2[i] = Wg[i];
    } else {
        const unsigned short* Wg = (const unsigned short*)WgP;
        for (int i = t; i < 2048; i += 256) Bs2[i] = bf2f(Wg[i]);
    }
    __syncthreads();
    for (int r = 0; r < 2; ++r) {
        int idx = t + 256 * r;
        int ni = idx / 16, o = idx % 16;
        const float* fe = &A2[ni * LDA2 + 128];
        float g = ldf(bgP, o, m);
        for (int j = 0; j < 128; ++j)
            g += fe[j] * Bs2[j * 16 + o];
        gates2[idx] = sigm_f(g);
    }
    __syncthreads();
    for (int r = 0; r < 6; ++r) {
        int idx = t + 256 * r;
        int ni = idx / 48, oc = idx % 48, o = oc / 3;
        int n = n0 + ni;
        float vres = 0.f;
        if (n < N_NODES)
            vres = ldf(vP, n * 48 + oc, m) + vureg[r] * gates2[ni * 16 + o];
        Bs2[ni * 48 + oc] = vres;
    }
    __syncthreads();
    if (t < NB) {
        const float* arow = &A2[t * LDA2];
        float sum = 0.f, sumsq = 0.f;
        for (int j = 0; j < 128; ++j) {
            float xr = arow[j] + arow[128 + j];
            sum += xr; sumsq += xr * xr;
        }
        float mu = sum * (1.f / 128.f);
        float var = sumsq * (1.f / 128.f) - mu * mu;
        mu_s[t] = mu;
        rstd_s[t] = rsqrtf(fmaxf(var, 0.f) + 1e-5f);
        const float* vr = &Bs2[t * 48];
        float accv = 0.f;
        for (int o = 0; o < 16; ++o) {
            float mm = vr[o*3]*vr[o*3] + vr[o*3+1]*vr[o*3+1] + vr[o*3+2]*vr[o*3+2];
            accv += fmaxf(mm, 1e-8f);
        }
        vn_s[t] = sqrtf(accv * (1.f / 16.f) + 1e-5f) + 1e-5f;
    }
    __syncthreads();
    float* outF = (float*)outP;
    unsigned short* outU = (unsigned short*)outP;
    for (int idx = t; idx < NB * 128; idx += 256) {
        int ni = idx >> 7, j = idx & 127;
        int n = n0 + ni;
        if (n < N_NODES) {
            float xr = A2[ni * LDA2 + j] + A2[ni * LDA2 + 128 + j];
            float o = (xr - mu_s[ni]) * rstd_s[ni] * ldf(lngP, j, m) + ldf(lnbP, j, m);
            if (m) outF[(size_t)n * 128 + j] = o;
            else   outU[(size_t)n * 128 + j] = f2bf(o);
        }
    }
    for (int idx = t; idx < NB * 48; idx += 256) {
        int ni = idx / 48, oc = idx % 48;
        int n = n0 + ni;
        if (n < N_NODES) {
            float o = Bs2[ni * 48 + oc] / vn_s[ni];
            if (m) outF[(size_t)N_NODES * 128 + (size_t)n * 48 + oc] = o;
            else   outU[(size_t)N_NODES * 128 + (size_t)n * 48 + oc] = f2bf(o);
        }
    }
}

extern "C" void kernel_launch(void* const* d_in, const int* in_sizes, int n_in,
                              void* d_out, int out_size, void* d_ws, size_t ws_size,
                              hipStream_t stream) {
    const int* ei = (const int*)d_in[17];

    // ws layout: flag(64B) | deg[N] | cursor[N] | row_ptr[N] | ssrc[E] | sdst[E]
    //            | agg_s[N*128] | agg_v[N*48]
    char* base = (char*)d_ws;
    int*   flag    = (int*)base;
    int*   deg     = (int*)(base + 64);
    int*   cursor  = deg + N_NODES;
    int*   row_ptr = cursor + N_NODES;
    int*   ssrc    = row_ptr + N_NODES;
    int*   sdst    = ssrc + E_EDGES;
    float* agg_s   = (float*)(sdst + E_EDGES);
    float* agg_v   = agg_s + (size_t)N_NODES * 128;

    hipMemsetAsync(d_ws, 0, 64 + (size_t)N_NODES * 4, stream);

    detect_kernel<<<1, 64, 0, stream>>>((const unsigned short*)d_in[0], flag);
    hist_kernel<<<(E_EDGES + 255) / 256, 256, 0, stream>>>(ei, deg);
    scan_kernel<<<1, 1024, 0, stream>>>(deg, cursor, row_ptr);
    scatter_kernel<<<(E_EDGES + 255) / 256, 256, 0, stream>>>(ei, cursor, ssrc, sdst);

    edge_kernel<<<N_NODES / (DPG * NGRP), 256, 0, stream>>>(
        d_in[0], d_in[1], d_in[2], d_in[3], d_in[4], d_in[5],
        d_in[6], d_in[7], d_in[8], row_ptr, ssrc, sdst, flag, agg_s, agg_v);
    node_kernel<<<(N_NODES + NB - 1) / NB, 256, 0, stream>>>(
        d_in[0], d_in[1], d_in[9], d_in[10], d_in[11], d_in[12],
        d_in[13], d_in[14], d_in[15], d_in[16], flag,
        agg_s, agg_v, (void*)d_out);
}

// Round 9
// 2596.652 us; speedup vs baseline: 1.4885x; 1.3959x over previous
//
#include <hip/hip_runtime.h>
#include <hip/hip_bf16.h>
#include <math.h>

#define N_NODES 50000
#define E_EDGES 800000
#define S_DIM 128
#define V_DIM 16
#define HM 17            // message GVP dim_h / vectors-in
#define KM 161           // 128 + 16 rbf + 17 sh
#define HU 32            // update GVP vectors-in
#define KU 288           // 256 + 32 sh

#define EB 32            // edges per tile
#define DPG 8            // dst nodes per agg-group
#define NGRP 2           // agg-groups per block -> 16 nodes/block
#define NB 32            // nodes per block (node kernel)
#define LDA2 292         // node A-tile leading dim (288 used)
#define KP 168           // bf16 row stride (336 B: 16B-aligned, 2-way-max banks)

typedef __attribute__((ext_vector_type(8))) short short8;
typedef __attribute__((ext_vector_type(4))) float floatx4;

__device__ __forceinline__ float bf2f(unsigned short u) {
    union { unsigned int i; float f; } w; w.i = ((unsigned int)u) << 16; return w.f;
}
__device__ __forceinline__ unsigned short f2bf(float f) {
    union { float f; unsigned int i; } w; w.f = f;
    unsigned int x = w.i;
    x += 0x7fff + ((x >> 16) & 1);
    return (unsigned short)(x >> 16);
}
__device__ __forceinline__ float silu_f(float x) { return x / (1.f + __expf(-x)); }
__device__ __forceinline__ float sigm_f(float x) { return 1.f / (1.f + __expf(-x)); }
__device__ __forceinline__ float ldf(const void* p, int i, int m) {
    if (m) return ((const float*)p)[i];
    return bf2f(((const unsigned short*)p)[i]);
}

// ---------------------------------------------------------------------------
// Detector: fp32 (flag=1) vs bf16 (flag=0) float inputs.
// ---------------------------------------------------------------------------
__global__ void detect_kernel(const unsigned short* __restrict__ s_us,
                              int* __restrict__ flag) {
    int t = threadIdx.x;
    int huge = 0;
    for (int k = 0; k < 16; ++k) {
        unsigned short u = s_us[2 * (t + 64 * k)];
        int e = (u >> 7) & 0xFF;
        if (e > 140) huge = 1;
    }
    if (huge) atomicOr(flag, 1);
}

// ---------------------------------------------------------------------------
// CSR build: histogram -> exclusive scan -> scatter.
// ---------------------------------------------------------------------------
__global__ __launch_bounds__(256) void hist_kernel(const int* __restrict__ ei,
                                                   int* __restrict__ deg) {
    int e = blockIdx.x * 256 + threadIdx.x;
    if (e < E_EDGES) atomicAdd(&deg[ei[E_EDGES + e]], 1);
}

__global__ __launch_bounds__(1024) void scan_kernel(const int* __restrict__ deg,
                                                    int* __restrict__ cursor,
                                                    int* __restrict__ row_ptr) {
    __shared__ int part[1024];
    const int t = threadIdx.x;
    const int CH = 49;                      // 1024*49 >= 50000
    int base = t * CH;
    int s = 0;
    for (int i = 0; i < CH; ++i) {
        int idx = base + i;
        if (idx < N_NODES) s += deg[idx];
    }
    part[t] = s;
    __syncthreads();
    if (t == 0) {
        int run = 0;
        for (int i = 0; i < 1024; ++i) { int tmp = part[i]; part[i] = run; run += tmp; }
    }
    __syncthreads();
    int run = part[t];
    for (int i = 0; i < CH; ++i) {
        int idx = base + i;
        if (idx < N_NODES) { cursor[idx] = run; row_ptr[idx] = run; run += deg[idx]; }
    }
}

__global__ __launch_bounds__(256) void scatter_kernel(const int* __restrict__ ei,
                                                      int* __restrict__ cursor,
                                                      int* __restrict__ ssrc,
                                                      int* __restrict__ sdst) {
    int e = blockIdx.x * 256 + threadIdx.x;
    if (e >= E_EDGES) return;
    int src = ei[e], dst = ei[E_EDGES + e];
    int pos = atomicAdd(&cursor[dst], 1);
    ssrc[pos] = src;
    sdst[pos] = dst;
}

// ---------------------------------------------------------------------------
// Edge kernel: block owns 16 dst nodes (2 groups of 8), CSR edges in 32-edge
// tiles. Wf^T resident in LDS as bf16; the 32x128x161 GEMM runs on MFMA
// (16x16x32 bf16, 5 k-tiles + scalar k=160 leftover). Zero global atomics.
// LDS 74.5 KB -> 2 blocks/CU.
// ---------------------------------------------------------------------------
__global__ __launch_bounds__(256, 2) void edge_kernel(
    const void* sP, const void* vP, const void* xP,
    const void* WhP, const void* WuP, const void* WfP,
    const void* bfP, const void* WgP, const void* bgP,
    const int* __restrict__ row_ptr,
    const int* __restrict__ ssrc,
    const int* __restrict__ sdst,
    const int* __restrict__ flagp,
    float* __restrict__ agg_s,               // [N][128]
    float* __restrict__ agg_v)               // [N][48]
{
    __shared__ unsigned short WfT[128 * KP]; // 43008 B: WfT[n][k] bf16
    __shared__ unsigned short Abf[EB * KP];  // 10752 B: A bf16 [e][k]; feats bf16 cols 0..127 post-GEMM
    __shared__ float vinB[EB * 51];          // 6528 B: vin -> mv[32][48]; Wu scratch early
    __shared__ float gatesS[EB * 16];        // 2048 B
    __shared__ unsigned int WgS[128 * 8];    // 4096 B packed bf16 pairs
    __shared__ float WhWu[HM * 16];          // 1088 B
    __shared__ float WhS[HM * HM];           // 1156 B
    __shared__ float agg[DPG * 176];         // 5632 B
    __shared__ int srcb[EB], dstb[EB];       // 256 B

    const int t = threadIdx.x;
    const int m = flagp[0];                  // 1 = fp32 inputs
    const int d0 = blockIdx.x * (DPG * NGRP);

    // ---- block-once staging ----
    if (m) {
        const float* Wh = (const float*)WhP;
        const float* Wu = (const float*)WuP;
        for (int i = t; i < HM * HM; i += 256) WhS[i] = Wh[i];
        for (int i = t; i < HM * 16; i += 256) vinB[i] = Wu[i];   // scratch
    } else {
        const unsigned short* Wh = (const unsigned short*)WhP;
        const unsigned short* Wu = (const unsigned short*)WuP;
        for (int i = t; i < HM * HM; i += 256) WhS[i] = bf2f(Wh[i]);
        for (int i = t; i < HM * 16; i += 256) vinB[i] = bf2f(Wu[i]);
    }
    // Wf -> WfT[n][k] bf16 (coalesced global reads: consecutive t -> consecutive n)
    for (int idx = t; idx < KM * 128; idx += 256) {
        int n = idx & 127, k = idx >> 7;
        WfT[n * KP + k] = f2bf(ldf(WfP, k * 128 + n, m));
    }
    // Wg -> packed bf16 pairs
    for (int idx = t; idx < 128 * 8; idx += 256) {
        int j = idx >> 3, p = idx & 7;
        float w0 = ldf(WgP, j * 16 + 2 * p, m);
        float w1 = ldf(WgP, j * 16 + 2 * p + 1, m);
        WgS[idx] = (unsigned int)f2bf(w0) | ((unsigned int)f2bf(w1) << 16);
    }
    __syncthreads();
    for (int idx = t; idx < HM * 16; idx += 256) {       // WhWu = Wh @ Wu
        int vv = idx / 16, o = idx % 16;
        float acc = 0.f;
        for (int h = 0; h < HM; ++h)
            acc += WhS[vv * HM + h] * vinB[h * 16 + o];
        WhWu[idx] = acc;
    }
    __syncthreads();                                     // vinB scratch free

    const int lane = t & 63, wave = t >> 6;
    const int quad = lane >> 4, l15 = lane & 15;
    const int n0 = wave * 32;                            // wave's 2 n-tiles
    const float bfc0 = ldf(bfP, n0 + l15, m);
    const float bfc1 = ldf(bfP, n0 + 16 + l15, m);
    const int go = t & 15;
    const float bg_r = ldf(bgP, go, m);
    const bool g_odd = (go & 1);
    const int g_p = go >> 1;

    for (int g = 0; g < NGRP; ++g) {
        const int dg = d0 + g * DPG;
        const int e_beg = row_ptr[dg];
        const int e_end = (dg + DPG >= N_NODES) ? E_EDGES : row_ptr[dg + DPG];
        for (int i = t; i < DPG * 176; i += 256) agg[i] = 0.f;
        __syncthreads();

        for (int et = e_beg; et < e_end; et += EB) {
            const int cnt = min(EB, e_end - et);
            if (t < EB) {
                srcb[t] = (t < cnt) ? ssrc[et + t] : 0;
                dstb[t] = (t < cnt) ? (sdst[et + t] - dg) : 0;
            }
            __syncthreads();
            // s-gather -> Abf cols 0..127 (bf16)
            {
                int cj = t & 31, ce = t >> 5;
                if (m) {
                    const float* sF = (const float*)sP;
                    for (int r = 0; r < 4; ++r) {
                        int e = ce + 8 * r;
                        float4 u = *(const float4*)(sF + (size_t)srcb[e] * S_DIM + cj * 4);
                        ushort4 pk = { f2bf(u.x), f2bf(u.y), f2bf(u.z), f2bf(u.w) };
                        *(ushort4*)&Abf[e * KP + cj * 4] = pk;
                    }
                } else {
                    const unsigned short* sU = (const unsigned short*)sP;
                    for (int r = 0; r < 4; ++r) {
                        int e = ce + 8 * r;
                        ushort4 u = *(const ushort4*)(sU + (size_t)srcb[e] * S_DIM + cj * 4);
                        *(ushort4*)&Abf[e * KP + cj * 4] = u;
                    }
                }
            }
            // vin + geometry/rbf
            if (t < 128) {
                int e = t >> 2, q = t & 3;
                int src = srcb[e];
                float* vin = &vinB[e * 51 + q * 12];
                if (m) {
                    const float* vp = (const float*)vP + (size_t)src * 48 + q * 12;
                    for (int i = 0; i < 3; ++i) {
                        float4 u = *(const float4*)(vp + i * 4);
                        vin[i * 4 + 0] = u.x; vin[i * 4 + 1] = u.y;
                        vin[i * 4 + 2] = u.z; vin[i * 4 + 3] = u.w;
                    }
                } else {
                    const unsigned short* vp = (const unsigned short*)vP + (size_t)src * 48 + q * 12;
                    for (int i = 0; i < 3; ++i) {
                        ushort4 u = *(const ushort4*)(vp + i * 4);
                        vin[i * 4 + 0] = bf2f(u.x); vin[i * 4 + 1] = bf2f(u.y);
                        vin[i * 4 + 2] = bf2f(u.z); vin[i * 4 + 3] = bf2f(u.w);
                    }
                }
                if (q == 0) {
                    int dst = dg + dstb[e];
                    float dxc[3]; float d2 = 0.f;
                    for (int c = 0; c < 3; ++c) {
                        float xs = ldf(xP, src * 3 + c, m);
                        float xd = ldf(xP, dst * 3 + c, m);
                        dxc[c] = xd - xs; d2 += dxc[c] * dxc[c];
                    }
                    float dist = sqrtf(fmaxf(d2, 1e-8f));
                    float inv = 1.f / dist;
                    for (int c = 0; c < 3; ++c) vinB[e * 51 + 48 + c] = dxc[c] * inv;
                    for (int k = 0; k < 16; ++k) {
                        float mu = (20.f / 15.f) * (float)k;
                        float z = (dist - mu) * (1.f / 1.25f);
                        Abf[e * KP + 128 + k] = f2bf(__expf(-z * z));
                    }
                }
            }
            __syncthreads();
            // sh -> Abf cols 144..160 (bf16)
            for (int idx = t; idx < EB * HM; idx += 256) {
                int e = idx / HM, h = idx % HM;
                const float* vin = &vinB[e * 51];
                float vh0 = 0.f, vh1 = 0.f, vh2 = 0.f;
                for (int vv = 0; vv < HM; ++vv) {
                    float w = WhS[vv * HM + h];
                    vh0 += vin[vv * 3 + 0] * w;
                    vh1 += vin[vv * 3 + 1] * w;
                    vh2 += vin[vv * 3 + 2] * w;
                }
                Abf[e * KP + 144 + h] =
                    f2bf(sqrtf(fmaxf(vh0 * vh0 + vh1 * vh1 + vh2 * vh2, 1e-8f)));
            }
            // Vu into registers
            float vureg[6];
            for (int r = 0; r < 6; ++r) {
                int idx = t + 256 * r;
                int e = idx / 48, oc = idx % 48, o = oc / 3, c = oc % 3;
                const float* vin = &vinB[e * 51];
                float acc = 0.f;
                for (int vv = 0; vv < HM; ++vv)
                    acc += vin[vv * 3 + c] * WhWu[vv * 16 + o];
                vureg[r] = acc;
            }
            __syncthreads();

            // ---- MFMA GEMM: feats[32][128] = A[32][161] @ Wf[161][128] ----
            floatx4 c00 = {0.f, 0.f, 0.f, 0.f}, c01 = c00, c10 = c00, c11 = c00;
            #pragma unroll
            for (int kt = 0; kt < 5; ++kt) {
                short8 a0 = *(const short8*)&Abf[(l15) * KP + kt * 32 + quad * 8];
                short8 a1 = *(const short8*)&Abf[(16 + l15) * KP + kt * 32 + quad * 8];
                short8 b0 = *(const short8*)&WfT[(n0 + l15) * KP + kt * 32 + quad * 8];
                short8 b1 = *(const short8*)&WfT[(n0 + 16 + l15) * KP + kt * 32 + quad * 8];
                c00 = __builtin_amdgcn_mfma_f32_16x16x32_bf16(a0, b0, c00, 0, 0, 0);
                c01 = __builtin_amdgcn_mfma_f32_16x16x32_bf16(a0, b1, c01, 0, 0, 0);
                c10 = __builtin_amdgcn_mfma_f32_16x16x32_bf16(a1, b0, c10, 0, 0, 0);
                c11 = __builtin_amdgcn_mfma_f32_16x16x32_bf16(a1, b1, c11, 0, 0, 0);
            }
            {   // leftover k = 160 (rank-1 update in C-layout)
                float w0 = bf2f(WfT[(n0 + l15) * KP + 160]);
                float w1 = bf2f(WfT[(n0 + 16 + l15) * KP + 160]);
                #pragma unroll
                for (int reg = 0; reg < 4; ++reg) {
                    float aa0 = bf2f(Abf[(quad * 4 + reg) * KP + 160]);
                    float aa1 = bf2f(Abf[(16 + quad * 4 + reg) * KP + 160]);
                    c00[reg] += aa0 * w0; c01[reg] += aa0 * w1;
                    c10[reg] += aa1 * w0; c11[reg] += aa1 * w1;
                }
            }
            __syncthreads();   // all A reads done before feats overwrite
            // epilogue: bias + silu -> bf16 feats into Abf cols 0..127
            #pragma unroll
            for (int reg = 0; reg < 4; ++reg) {
                int e0r = quad * 4 + reg, e1r = 16 + quad * 4 + reg;
                Abf[e0r * KP + n0 + l15]      = f2bf(silu_f(c00[reg] + bfc0));
                Abf[e0r * KP + n0 + 16 + l15] = f2bf(silu_f(c01[reg] + bfc1));
                Abf[e1r * KP + n0 + l15]      = f2bf(silu_f(c10[reg] + bfc0));
                Abf[e1r * KP + n0 + 16 + l15] = f2bf(silu_f(c11[reg] + bfc1));
            }
            __syncthreads();
            // gates[e][o] = sigmoid(feats @ Wg + bg)
            for (int r = 0; r < 2; ++r) {
                int e = (t + 256 * r) >> 4;
                const unsigned short* fe = &Abf[e * KP];
                float gv = bg_r;
                for (int j = 0; j < 128; ++j) {
                    unsigned int u = WgS[j * 8 + g_p];
                    union { unsigned int i; float f; } w;
                    w.i = g_odd ? (u & 0xFFFF0000u) : (u << 16);
                    gv += bf2f(fe[j]) * w.f;
                }
                gatesS[e * 16 + go] = sigm_f(gv);
            }
            __syncthreads();
            // mv -> vinB[e*48+oc]
            for (int r = 0; r < 6; ++r) {
                int idx = t + 256 * r;
                int e = idx / 48, oc = idx % 48, o = oc / 3;
                vinB[e * 48 + oc] = vureg[r] * gatesS[e * 16 + o];
            }
            __syncthreads();
            // run-flush into agg (single writer per column)
            if (t < 176) {
                int c = t;
                float racc = 0.f;
                for (int e = 0; e < cnt; ++e) {
                    racc += (c < 128) ? bf2f(Abf[e * KP + c]) : vinB[e * 48 + (c - 128)];
                    bool flush = (e == cnt - 1) || (dstb[e + 1] != dstb[e]);
                    if (flush) { agg[dstb[e] * 176 + c] += racc; racc = 0.f; }
                }
            }
            __syncthreads();
        }
        // store group agg (plain coalesced stores, exclusive ownership)
        for (int idx = t; idx < DPG * 176; idx += 256) {
            int d = idx / 176, c = idx % 176;
            int n = dg + d;
            if (c < 128) agg_s[(size_t)n * 128 + c] = agg[idx];
            else         agg_v[(size_t)n * 48 + (c - 128)] = agg[idx];
        }
        __syncthreads();
    }
}

// ---------------------------------------------------------------------------
// Node (update) kernel: per block, 32 nodes. Update GVP + residual + LN.
// ---------------------------------------------------------------------------
__global__ __launch_bounds__(256) void node_kernel(
    const void* sP, const void* vP,
    const void* WhP, const void* WuP, const void* WfP,
    const void* bfP, const void* WgP, const void* bgP,
    const void* lngP, const void* lnbP,
    const int* __restrict__ flagp,
    const float* __restrict__ agg_s,         // [N][128]
    const float* __restrict__ agg_v,         // [N][48]
    void* outP)                              // [N*128] then [N*48]
{
    __shared__ float A2[NB * LDA2];
    __shared__ float Bs2[4096];
    __shared__ float WhWu2[HU * 16];
    __shared__ float gates2[NB * 16];
    __shared__ float WhS[HU * HU];
    __shared__ float mu_s[NB], rstd_s[NB], vn_s[NB];

    const int t = threadIdx.x;
    const int n0 = blockIdx.x * NB;
    const int m = flagp[0];

    if (m) {
        const float* Wh = (const float*)WhP;
        const float* Wu = (const float*)WuP;
        for (int i = t; i < HU * HU; i += 256) WhS[i] = Wh[i];
        for (int i = t; i < HU * 16; i += 256) gates2[i] = Wu[i];
    } else {
        const unsigned short* Wh = (const unsigned short*)WhP;
        const unsigned short* Wu = (const unsigned short*)WuP;
        for (int i = t; i < HU * HU; i += 256) WhS[i] = bf2f(Wh[i]);
        for (int i = t; i < HU * 16; i += 256) gates2[i] = bf2f(Wu[i]);
    }
    if (m) {
        const float* sF = (const float*)sP;
        for (int idx = t; idx < NB * 32; idx += 256) {
            int ni = idx >> 5, col4 = (idx & 31) * 4;
            int n = n0 + ni;
            float* a = &A2[ni * LDA2 + col4];
            if (n < N_NODES) {
                float4 u = *(const float4*)(sF + (size_t)n * 128 + col4);
                a[0] = u.x; a[1] = u.y; a[2] = u.z; a[3] = u.w;
            } else { a[0] = a[1] = a[2] = a[3] = 0.f; }
        }
    } else {
        const unsigned short* sU = (const unsigned short*)sP;
        for (int idx = t; idx < NB * 32; idx += 256) {
            int ni = idx >> 5, col4 = (idx & 31) * 4;
            int n = n0 + ni;
            float* a = &A2[ni * LDA2 + col4];
            if (n < N_NODES) {
                ushort4 u = *(const ushort4*)(sU + (size_t)n * 128 + col4);
                a[0] = bf2f(u.x); a[1] = bf2f(u.y); a[2] = bf2f(u.z); a[3] = bf2f(u.w);
            } else { a[0] = a[1] = a[2] = a[3] = 0.f; }
        }
    }
    for (int idx = t; idx < NB * 32; idx += 256) {
        int ni = idx >> 5, col4 = (idx & 31) * 4;
        int n = n0 + ni;
        float* a = &A2[ni * LDA2 + 128 + col4];
        if (n < N_NODES) {
            float4 u = *(const float4*)(agg_s + (size_t)n * 128 + col4);
            a[0] = u.x * 0.1f; a[1] = u.y * 0.1f; a[2] = u.z * 0.1f; a[3] = u.w * 0.1f;
        } else { a[0] = a[1] = a[2] = a[3] = 0.f; }
    }
    for (int idx = t; idx < NB * 96; idx += 256) {
        int ni = idx / 96, vc = idx % 96;
        int n = n0 + ni;
        float val = 0.f;
        if (n < N_NODES)
            val = (vc < 48) ? ldf(vP, n * 48 + vc, m)
                            : agg_v[(size_t)n * 48 + (vc - 48)] * 0.1f;
        Bs2[ni * 100 + vc] = val;
    }
    __syncthreads();
    for (int idx = t; idx < HU * 16; idx += 256) {
        int vv = idx / 16, o = idx % 16;
        float acc = 0.f;
        for (int h = 0; h < HU; ++h)
            acc += WhS[vv * HU + h] * gates2[h * 16 + o];
        WhWu2[idx] = acc;
    }
    for (int idx = t; idx < NB * HU; idx += 256) {
        int ni = idx / HU, h = idx % HU;
        const float* vc = &Bs2[ni * 100];
        float vh0 = 0.f, vh1 = 0.f, vh2 = 0.f;
        for (int vv = 0; vv < HU; ++vv) {
            float w = WhS[vv * HU + h];
            vh0 += vc[vv * 3 + 0] * w; vh1 += vc[vv * 3 + 1] * w; vh2 += vc[vv * 3 + 2] * w;
        }
        A2[ni * LDA2 + 256 + h] = sqrtf(fmaxf(vh0 * vh0 + vh1 * vh1 + vh2 * vh2, 1e-8f));
    }
    __syncthreads();
    float vureg[6];
    for (int r = 0; r < 6; ++r) {
        int idx = t + 256 * r;
        int ni = idx / 48, oc = idx % 48, o = oc / 3, c = oc % 3;
        const float* vc = &Bs2[ni * 100];
        float acc = 0.f;
        for (int vv = 0; vv < HU; ++vv)
            acc += vc[vv * 3 + c] * WhWu2[vv * 16 + o];
        vureg[r] = acc;
    }
    __syncthreads();

    const int tj = t & 15, tn = t >> 4;
    const int nb = tn * 2;
    float acc[2][8];
    #pragma unroll
    for (int i = 0; i < 2; ++i)
        #pragma unroll
        for (int j = 0; j < 8; ++j) acc[i][j] = 0.f;

    for (int kk = 0; kk < KU; kk += 32) {
        if (m) {
            const float* WfF = (const float*)WfP;
            for (int idx = t; idx < 32 * 32; idx += 256) {
                int kt = idx >> 5, col4 = (idx & 31) * 4;
                float4 u = *(const float4*)(WfF + (size_t)(kk + kt) * 128 + col4);
                float* b = &Bs2[kt * 128 + col4];
                b[0] = u.x; b[1] = u.y; b[2] = u.z; b[3] = u.w;
            }
        } else {
            const unsigned short* WfU = (const unsigned short*)WfP;
            for (int idx = t; idx < 32 * 32; idx += 256) {
                int kt = idx >> 5, col4 = (idx & 31) * 4;
                ushort4 u = *(const ushort4*)(WfU + (size_t)(kk + kt) * 128 + col4);
                float* b = &Bs2[kt * 128 + col4];
                b[0] = bf2f(u.x); b[1] = bf2f(u.y); b[2] = bf2f(u.z); b[3] = bf2f(u.w);
            }
        }
        __syncthreads();
        for (int kt = 0; kt < 32; ++kt) {
            float a0 = A2[(nb + 0) * LDA2 + kk + kt];
            float a1 = A2[(nb + 1) * LDA2 + kk + kt];
            const float* brow = &Bs2[kt * 128 + tj];
            #pragma unroll
            for (int jj = 0; jj < 8; ++jj) {
                float b = brow[16 * jj];
                acc[0][jj] += a0 * b; acc[1][jj] += a1 * b;
            }
        }
        __syncthreads();
    }
    float breg[8];
    #pragma unroll
    for (int jj = 0; jj < 8; ++jj) breg[jj] = ldf(bfP, tj + 16 * jj, m);
    #pragma unroll
    for (int i = 0; i < 2; ++i) {
        float* aout = &A2[(nb + i) * LDA2 + 128];
        #pragma unroll
        for (int jj = 0; jj < 8; ++jj) {
            int col = tj + 16 * jj;
            aout[col] = silu_f(acc[i][jj] + breg[jj]);
        }
    }
    __syncthreads();
    if (m) {
        const float* Wg = (const float*)WgP;
        for (int i = t; i < 2048; i += 256) Bs2[i] = Wg[i];
    } else {
        const unsigned short* Wg = (const unsigned short*)WgP;
        for (int i = t; i < 2048; i += 256) Bs2[i] = bf2f(Wg[i]);
    }
    __syncthreads();
    for (int r = 0; r < 2; ++r) {
        int idx = t + 256 * r;
        int ni = idx / 16, o = idx % 16;
        const float* fe = &A2[ni * LDA2 + 128];
        float g = ldf(bgP, o, m);
        for (int j = 0; j < 128; ++j)
            g += fe[j] * Bs2[j * 16 + o];
        gates2[idx] = sigm_f(g);
    }
    __syncthreads();
    for (int r = 0; r < 6; ++r) {
        int idx = t + 256 * r;
        int ni = idx / 48, oc = idx % 48, o = oc / 3;
        int n = n0 + ni;
        float vres = 0.f;
        if (n < N_NODES)
            vres = ldf(vP, n * 48 + oc, m) + vureg[r] * gates2[ni * 16 + o];
        Bs2[ni * 48 + oc] = vres;
    }
    __syncthreads();
    if (t < NB) {
        const float* arow = &A2[t * LDA2];
        float sum = 0.f, sumsq = 0.f;
        for (int j = 0; j < 128; ++j) {
            float xr = arow[j] + arow[128 + j];
            sum += xr; sumsq += xr * xr;
        }
        float mu = sum * (1.f / 128.f);
        float var = sumsq * (1.f / 128.f) - mu * mu;
        mu_s[t] = mu;
        rstd_s[t] = rsqrtf(fmaxf(var, 0.f) + 1e-5f);
        const float* vr = &Bs2[t * 48];
        float accv = 0.f;
        for (int o = 0; o < 16; ++o) {
            float mm = vr[o*3]*vr[o*3] + vr[o*3+1]*vr[o*3+1] + vr[o*3+2]*vr[o*3+2];
            accv += fmaxf(mm, 1e-8f);
        }
        vn_s[t] = sqrtf(accv * (1.f / 16.f) + 1e-5f) + 1e-5f;
    }
    __syncthreads();
    float* outF = (float*)outP;
    unsigned short* outU = (unsigned short*)outP;
    for (int idx = t; idx < NB * 128; idx += 256) {
        int ni = idx >> 7, j = idx & 127;
        int n = n0 + ni;
        if (n < N_NODES) {
            float xr = A2[ni * LDA2 + j] + A2[ni * LDA2 + 128 + j];
            float o = (xr - mu_s[ni]) * rstd_s[ni] * ldf(lngP, j, m) + ldf(lnbP, j, m);
            if (m) outF[(size_t)n * 128 + j] = o;
            else   outU[(size_t)n * 128 + j] = f2bf(o);
        }
    }
    for (int idx = t; idx < NB * 48; idx += 256) {
        int ni = idx / 48, oc = idx % 48;
        int n = n0 + ni;
        if (n < N_NODES) {
            float o = Bs2[ni * 48 + oc] / vn_s[ni];
            if (m) outF[(size_t)N_NODES * 128 + (size_t)n * 48 + oc] = o;
            else   outU[(size_t)N_NODES * 128 + (size_t)n * 48 + oc] = f2bf(o);
        }
    }
}

extern "C" void kernel_launch(void* const* d_in, const int* in_sizes, int n_in,
                              void* d_out, int out_size, void* d_ws, size_t ws_size,
                              hipStream_t stream) {
    const int* ei = (const int*)d_in[17];

    // ws layout: flag(64B) | deg[N] | cursor[N] | row_ptr[N] | ssrc[E] | sdst[E]
    //            | agg_s[N*128] | agg_v[N*48]
    char* base = (char*)d_ws;
    int*   flag    = (int*)base;
    int*   deg     = (int*)(base + 64);
    int*   cursor  = deg + N_NODES;
    int*   row_ptr = cursor + N_NODES;
    int*   ssrc    = row_ptr + N_NODES;
    int*   sdst    = ssrc + E_EDGES;
    float* agg_s   = (float*)(sdst + E_EDGES);
    float* agg_v   = agg_s + (size_t)N_NODES * 128;

    (void)hipMemsetAsync(d_ws, 0, 64 + (size_t)N_NODES * 4, stream);

    detect_kernel<<<1, 64, 0, stream>>>((const unsigned short*)d_in[0], flag);
    hist_kernel<<<(E_EDGES + 255) / 256, 256, 0, stream>>>(ei, deg);
    scan_kernel<<<1, 1024, 0, stream>>>(deg, cursor, row_ptr);
    scatter_kernel<<<(E_EDGES + 255) / 256, 256, 0, stream>>>(ei, cursor, ssrc, sdst);

    edge_kernel<<<N_NODES / (DPG * NGRP), 256, 0, stream>>>(
        d_in[0], d_in[1], d_in[2], d_in[3], d_in[4], d_in[5],
        d_in[6], d_in[7], d_in[8], row_ptr, ssrc, sdst, flag, agg_s, agg_v);
    node_kernel<<<(N_NODES + NB - 1) / NB, 256, 0, stream>>>(
        d_in[0], d_in[1], d_in[9], d_in[10], d_in[11], d_in[12],
        d_in[13], d_in[14], d_in[15], d_in[16], flag,
        agg_s, agg_v, (void*)d_out);
}